// Round 4
// baseline (3688.331 us; speedup 1.0000x reference)
//
#include <hip/hip_runtime.h>

#define NPTS 256
#define NBATCH 64
#define BIGF 1e30f
#define KBIG 0x7149F200u   // __float_as_uint(1e30f) & 0xFFFFFF00

__device__ __forceinline__ float rlane(float v, int l) {
    return __uint_as_float((unsigned int)__builtin_amdgcn_readlane((int)__float_as_uint(v), l));
}
__device__ __forceinline__ int rlanei(int v, int l) {
    return __builtin_amdgcn_readlane(v, l);
}
__device__ __forceinline__ float rawsqrt(float x) {
    return __builtin_amdgcn_sqrtf(x);
}

// Uniform-slot select (slot wave-uniform); cold paths only.
#define SEL4(a, s) ((s) == 0 ? a[0] : (s) == 1 ? a[1] : (s) == 2 ? a[2] : a[3])

#define DPP_UMIN(v, ctrl) \
    (min)((v), (unsigned int)__builtin_amdgcn_update_dpp( \
        (int)(v), (int)(v), (ctrl), 0xf, 0xf, false))

__global__ void zero_out_kernel(float* out, int n) {
    int i = blockIdx.x * blockDim.x + threadIdx.x;
    if (i < n) out[i] = 0.0f;
}

// ================= R17: two independent batches (A,B) per wave =================
// R13 hot dataflow, split into phase macros so the two problems' dependent
// chains interleave in one basic block (ILP hides DPP/readlane/branch latency).
// Falsified levers (R14 duals / R15 multi-source / R16 free-argmin claims) all
// confirm: trees are near-complete, time = F * 256 * chain-latency. R17 attacks
// chain-latency occupancy instead of step count.

#define DECL_STATE(S)                                                            \
    float prx##S[4], pry##S[4], prz##S[4];                                       \
    float tx##S[4], ty##S[4], tz##S[4];                                          \
    float vv##S[4], upc##S[4], Tv##S[4], w##S[4], vsave##S[4];                   \
    float rxc##S[4], ryc##S[4], rzc##S[4];                                       \
    unsigned int kMv##S[4];                                                      \
    int pc##S[4] = {-1, -1, -1, -1};                                             \
    int way##S[4];                                                               \
    unsigned long long freem##S[4];                                              \
    unsigned long long frm##S[4];                                                \
    float bx##S, by##S, bz##S, rootx##S, rooty##S, rootz##S;                     \
    int j0##S, jfin##S, root##S, usedm##S;                                       \
    float D##S;                                                                  \
    bool active##S = false, aug##S = false;                                      \
    unsigned int kk##S;

// Loads + Phase 1a (column reduction) + Phase 1b (greedy claim) for problem S.
#define PHASE1(S, pb_, tb_)                                                      \
    {                                                                            \
        _Pragma("unroll")                                                        \
        for (int c = 0; c < 4; ++c) {                                            \
            int idx = c * 64 + lane;                                             \
            prx##S[c] = pb_[idx*3+0]; pry##S[c] = pb_[idx*3+1]; prz##S[c] = pb_[idx*3+2]; \
            tx##S[c]  = tb_[idx*3+0]; ty##S[c]  = tb_[idx*3+1]; tz##S[c]  = tb_[idx*3+2]; \
            upc##S[c] = 0.f; Tv##S[c] = 0.f; vsave##S[c] = 0.f;                  \
            rxc##S[c] = 0.f; ryc##S[c] = 0.f; rzc##S[c] = 0.f;                   \
            freem##S[c] = ~0ull;                                                 \
        }                                                                        \
        float colmin[4] = {BIGF, BIGF, BIGF, BIGF};                              \
        int   colrow[4] = {0, 0, 0, 0};                                          \
        _Pragma("unroll")                                                        \
        for (int rs = 0; rs < 4; ++rs) {                                         \
            for (int rl = 0; rl < 64; ++rl) {                                    \
                float bx = rlane(prx##S[rs], rl), by = rlane(pry##S[rs], rl), bz = rlane(prz##S[rs], rl); \
                int r = rs * 64 + rl;                                            \
                _Pragma("unroll")                                                \
                for (int c = 0; c < 4; ++c) {                                    \
                    float dx = bx - tx##S[c], dy = by - ty##S[c], dz = bz - tz##S[c]; \
                    float d = rawsqrt(dx*dx + dy*dy + dz*dz);                    \
                    if (d < colmin[c]) { colmin[c] = d; colrow[c] = r; }         \
                }                                                                \
            }                                                                    \
        }                                                                        \
        _Pragma("unroll")                                                        \
        for (int c = 0; c < 4; ++c) vv##S[c] = colmin[c];                        \
        frm##S[0] = frm##S[1] = frm##S[2] = frm##S[3] = ~0ull;                   \
        _Pragma("unroll")                                                        \
        for (int cs = 0; cs < 4; ++cs) {                                         \
            for (int l = 0; l < 64; ++l) {                                       \
                int r = rlanei(colrow[cs], l);                                   \
                int rs = r >> 6, rl2 = r & 63;                                   \
                unsigned long long bit = 1ull << rl2;                            \
                bool free_row = (SEL4(frm##S, rs) & bit) != 0ull;                \
                if (free_row) {                                                  \
                    _Pragma("unroll")                                            \
                    for (int s = 0; s < 4; ++s) if (s == rs) frm##S[s] &= ~bit;  \
                    float bx, by, bz;                                            \
                    switch (rs) {                                                \
                        case 0:  bx = rlane(prx##S[0], rl2); by = rlane(pry##S[0], rl2); bz = rlane(prz##S[0], rl2); break; \
                        case 1:  bx = rlane(prx##S[1], rl2); by = rlane(pry##S[1], rl2); bz = rlane(prz##S[1], rl2); break; \
                        case 2:  bx = rlane(prx##S[2], rl2); by = rlane(pry##S[2], rl2); bz = rlane(prz##S[2], rl2); break; \
                        default: bx = rlane(prx##S[3], rl2); by = rlane(pry##S[3], rl2); bz = rlane(prz##S[3], rl2); break; \
                    }                                                            \
                    if (lane == l) {                                             \
                        pc##S[cs] = r; upc##S[cs] = 0.f;                         \
                        rxc##S[cs] = bx; ryc##S[cs] = by; rzc##S[cs] = bz;       \
                    }                                                            \
                    _Pragma("unroll")                                            \
                    for (int s = 0; s < 4; ++s)                                  \
                        if (s == cs) freem##S[s] &= ~(1ull << l);                \
                }                                                                \
            }                                                                    \
        }                                                                        \
    }

// Pop next free row of S, set up a fresh Dijkstra search (cold).
#define INIT_SEARCH(S)                                                           \
    {                                                                            \
        int is_, il_;                                                            \
        if (frm##S[0])      { is_ = 0; il_ = (int)__builtin_ctzll(frm##S[0]); }  \
        else if (frm##S[1]) { is_ = 1; il_ = (int)__builtin_ctzll(frm##S[1]); }  \
        else if (frm##S[2]) { is_ = 2; il_ = (int)__builtin_ctzll(frm##S[2]); }  \
        else                { is_ = 3; il_ = (int)__builtin_ctzll(frm##S[3]); }  \
        _Pragma("unroll")                                                        \
        for (int s = 0; s < 4; ++s)                                              \
            if (s == is_) frm##S[s] &= (frm##S[s] - 1);                          \
        root##S = is_ * 64 + il_;                                                \
        switch (is_) {                                                           \
            case 0:  rootx##S = rlane(prx##S[0], il_); rooty##S = rlane(pry##S[0], il_); rootz##S = rlane(prz##S[0], il_); break; \
            case 1:  rootx##S = rlane(prx##S[1], il_); rooty##S = rlane(pry##S[1], il_); rootz##S = rlane(prz##S[1], il_); break; \
            case 2:  rootx##S = rlane(prx##S[2], il_); rooty##S = rlane(pry##S[2], il_); rootz##S = rlane(prz##S[2], il_); break; \
            default: rootx##S = rlane(prx##S[3], il_); rooty##S = rlane(pry##S[3], il_); rootz##S = rlane(prz##S[3], il_); break; \
        }                                                                        \
        _Pragma("unroll")                                                        \
        for (int c = 0; c < 4; ++c) {                                            \
            kMv##S[c] = KBIG | colu[c];                                          \
            w##S[c]   = -vv##S[c];                                               \
        }                                                                        \
        usedm##S = 0;                                                            \
        bx##S = rootx##S; by##S = rooty##S; bz##S = rootz##S;                    \
        j0##S = -1; jfin##S = 0; D##S = 0.f;                                     \
        aug##S = false; active##S = true;                                        \
    }

// Hot phase 1: relax all 256 columns against current tree row (branch-free).
#define RELAX(S)                                                                 \
    {                                                                            \
        _Pragma("unroll")                                                        \
        for (int c = 0; c < 4; ++c) {                                            \
            float dx = bx##S - tx##S[c], dy = by##S - ty##S[c], dz = bz##S - tz##S[c]; \
            float d = rawsqrt(dx*dx + dy*dy + dz*dz);                            \
            float cand = d + w##S[c];                                            \
            unsigned int kc = (__float_as_uint(cand) & 0xFFFFFF00u) | colu[c];   \
            if (kc < kMv##S[c]) { kMv##S[c] = kc; way##S[c] = j0##S; }           \
        }                                                                        \
    }

// Hot phase 2: 64-lane packed-key min -> kk##S (branch-free).
#define REDUCE(S)                                                                \
    {                                                                            \
        unsigned int vr = (min)((min)(kMv##S[0], kMv##S[1]),                     \
                                (min)(kMv##S[2], kMv##S[3]));                    \
        vr = DPP_UMIN(vr, 0x111);   /* row_shr:1 */                              \
        vr = DPP_UMIN(vr, 0x112);   /* row_shr:2 */                              \
        vr = DPP_UMIN(vr, 0x114);   /* row_shr:4 */                              \
        const unsigned int q0 = (unsigned int)rlanei((int)vr, 7);                \
        const unsigned int q1 = (unsigned int)rlanei((int)vr, 15);               \
        const unsigned int q2 = (unsigned int)rlanei((int)vr, 23);               \
        const unsigned int q3 = (unsigned int)rlanei((int)vr, 31);               \
        const unsigned int q4 = (unsigned int)rlanei((int)vr, 39);               \
        const unsigned int q5 = (unsigned int)rlanei((int)vr, 47);               \
        const unsigned int q6 = (unsigned int)rlanei((int)vr, 55);               \
        const unsigned int q7 = (unsigned int)rlanei((int)vr, 63);               \
        kk##S = (min)((min)((min)(q0, q1), (min)(q2, q3)),                       \
                      (min)((min)(q4, q5), (min)(q6, q7)));                      \
    }

// Hot phase 3: fetch winner, free-test (-> aug flag), else freeze + w update.
#define FETCH(S)                                                                 \
    {                                                                            \
        const int   j1   = (int)(kk##S & 0xFFu);                                 \
        const float gmin = __uint_as_float(kk##S & 0xFFFFFF00u);                 \
        const int osl = j1 >> 6, oln = j1 & 63;                                  \
        float uj, nbx, nby, nbz;                                                 \
        switch (osl) {                                                           \
            case 0:  uj = rlane(upc##S[0], oln); nbx = rlane(rxc##S[0], oln); nby = rlane(ryc##S[0], oln); nbz = rlane(rzc##S[0], oln); break; \
            case 1:  uj = rlane(upc##S[1], oln); nbx = rlane(rxc##S[1], oln); nby = rlane(ryc##S[1], oln); nbz = rlane(rzc##S[1], oln); break; \
            case 2:  uj = rlane(upc##S[2], oln); nbx = rlane(rxc##S[2], oln); nby = rlane(ryc##S[2], oln); nbz = rlane(rzc##S[2], oln); break; \
            default: uj = rlane(upc##S[3], oln); nbx = rlane(rxc##S[3], oln); nby = rlane(ryc##S[3], oln); nbz = rlane(rzc##S[3], oln); break; \
        }                                                                        \
        const unsigned long long fm = SEL4(freem##S, osl);                       \
        if ((fm >> oln) & 1ull) {                                                \
            jfin##S = j1; D##S = gmin; aug##S = true;                            \
        } else {                                                                 \
            _Pragma("unroll")                                                    \
            for (int c = 0; c < 4; ++c)                                          \
                if (c == osl && lane == oln) {                                   \
                    usedm##S |= (1 << c);                                        \
                    Tv##S[c] = gmin;                                             \
                    vsave##S[c] = vv##S[c];                                      \
                    vv##S[c] = -BIGF;           /* -> w = +BIGF -> excluded */   \
                    kMv##S[c] = KBIG | colu[c]; /* frozen */                     \
                }                                                                \
            const float gu = gmin - uj;                                          \
            _Pragma("unroll")                                                    \
            for (int c = 0; c < 4; ++c) w##S[c] = gu - vv##S[c];                 \
            bx##S = nbx; by##S = nby; bz##S = nbz;                               \
            j0##S = j1;                                                          \
        }                                                                        \
    }

// Cold: dual commit + free-column retire + alternating-path augment for S.
#define COMMIT_AUG(S)                                                            \
    {                                                                            \
        _Pragma("unroll")                                                        \
        for (int c = 0; c < 4; ++c)                                              \
            if ((usedm##S >> c) & 1) {                                           \
                vv##S[c] = vsave##S[c] + Tv##S[c] - D##S;                        \
                upc##S[c] += D##S - Tv##S[c];                                    \
            }                                                                    \
        {                                                                        \
            const int wsl = jfin##S >> 6;                                        \
            const unsigned long long bit = 1ull << (jfin##S & 63);               \
            _Pragma("unroll")                                                    \
            for (int s = 0; s < 4; ++s)                                          \
                if (s == wsl) freem##S[s] &= ~bit;                               \
        }                                                                        \
        int jc = jfin##S;                                                        \
        while (true) {                                                           \
            const int osl = jc >> 6, oln = jc & 63;                              \
            int jw;                                                              \
            switch (osl) {                                                       \
                case 0:  jw = rlanei(way##S[0], oln); break;                     \
                case 1:  jw = rlanei(way##S[1], oln); break;                     \
                case 2:  jw = rlanei(way##S[2], oln); break;                     \
                default: jw = rlanei(way##S[3], oln); break;                     \
            }                                                                    \
            int np_; float nup, nrx, nry, nrz;                                   \
            if (jw < 0) {                                                        \
                np_ = root##S; nup = D##S;                                       \
                nrx = rootx##S; nry = rooty##S; nrz = rootz##S;                  \
            } else {                                                             \
                const int wsl = jw >> 6, wln = jw & 63;                          \
                switch (wsl) {                                                   \
                    case 0:  np_ = rlanei(pc##S[0], wln); nup = rlane(upc##S[0], wln); nrx = rlane(rxc##S[0], wln); nry = rlane(ryc##S[0], wln); nrz = rlane(rzc##S[0], wln); break; \
                    case 1:  np_ = rlanei(pc##S[1], wln); nup = rlane(upc##S[1], wln); nrx = rlane(rxc##S[1], wln); nry = rlane(ryc##S[1], wln); nrz = rlane(rzc##S[1], wln); break; \
                    case 2:  np_ = rlanei(pc##S[2], wln); nup = rlane(upc##S[2], wln); nrx = rlane(rxc##S[2], wln); nry = rlane(ryc##S[2], wln); nrz = rlane(rzc##S[2], wln); break; \
                    default: np_ = rlanei(pc##S[3], wln); nup = rlane(upc##S[3], wln); nrx = rlane(rxc##S[3], wln); nry = rlane(ryc##S[3], wln); nrz = rlane(rzc##S[3], wln); break; \
                }                                                                \
            }                                                                    \
            _Pragma("unroll")                                                    \
            for (int c = 0; c < 4; ++c)                                          \
                if (c == osl && lane == oln) {                                   \
                    pc##S[c] = np_; upc##S[c] = nup;                             \
                    rxc##S[c] = nrx; ryc##S[c] = nry; rzc##S[c] = nrz;           \
                }                                                                \
            if (jw < 0) break;                                                   \
            jc = jw;                                                             \
        }                                                                        \
    }

#define HAS_FREE(S) (frm##S[0] | frm##S[1] | frm##S[2] | frm##S[3])

// One wave per TWO batches (A = blockIdx, B = blockIdx + 32).
__launch_bounds__(64, 1)
__global__ void hungarian_wave(const float* __restrict__ pred,
                               const float* __restrict__ target,
                               float* __restrict__ out) {
    const int lane = threadIdx.x;
    const int bA = blockIdx.x;
    const int bB = blockIdx.x + (NBATCH / 2);

    const float* pbA = pred   + (size_t)bA * NPTS * 3;
    const float* tbA = target + (size_t)bA * NPTS * 3;
    const float* pbB = pred   + (size_t)bB * NPTS * 3;
    const float* tbB = target + (size_t)bB * NPTS * 3;

    unsigned int colu[4];              // shared: lane's column ids
#pragma unroll
    for (int c = 0; c < 4; ++c) colu[c] = (unsigned int)(c * 64 + lane);

    DECL_STATE(A)
    DECL_STATE(B)

    PHASE1(A, pbA, tbA)
    PHASE1(B, pbB, tbB)

    // ---- Phase 2: paired Dijkstra searches, chains interleaved for ILP ----
    while (true) {
        if (!activeA && HAS_FREE(A)) INIT_SEARCH(A)
        if (!activeB && HAS_FREE(B)) INIT_SEARCH(B)
        if (!activeA && !activeB) break;

        if (activeA && activeB) {
            // Merged hot loop: branch-free RELAX/REDUCE of both problems share
            // one basic block; B's issue fills A's DPP/readlane stalls.
            do {
                RELAX(A)
                RELAX(B)
                REDUCE(A)
                REDUCE(B)
                FETCH(A)
                FETCH(B)
            } while (!(augA | augB));
        } else if (activeA) {
            do {
                RELAX(A)
                REDUCE(A)
                FETCH(A)
            } while (!augA);
        } else {
            do {
                RELAX(B)
                REDUCE(B)
                FETCH(B)
            } while (!augB);
        }

        if (augA) { COMMIT_AUG(A) activeA = false; augA = false; }
        if (augB) { COMMIT_AUG(B) activeB = false; augB = false; }
    }

    // ---- Matched cost for both problems (IEEE sqrt for final accuracy) ----
    float s = 0.f;
#pragma unroll
    for (int c = 0; c < 4; ++c) {
        float dxA = rxcA[c] - txA[c], dyA = rycA[c] - tyA[c], dzA = rzcA[c] - tzA[c];
        s += sqrtf(dxA * dxA + dyA * dyA + dzA * dzA);
        float dxB = rxcB[c] - txB[c], dyB = rycB[c] - tyB[c], dzB = rzcB[c] - tzB[c];
        s += sqrtf(dxB * dxB + dyB * dyB + dzB * dzB);
    }
#pragma unroll
    for (int off = 1; off < 64; off <<= 1) s += __shfl_xor(s, off, 64);
    if (lane == 0) atomicAdd(out, s / (float)NBATCH);
}

extern "C" void kernel_launch(void* const* d_in, const int* in_sizes, int n_in,
                              void* d_out, int out_size, void* d_ws, size_t ws_size,
                              hipStream_t stream) {
    const float* pred   = (const float*)d_in[0];
    const float* target = (const float*)d_in[1];
    float* out = (float*)d_out;

    zero_out_kernel<<<1, 64, 0, stream>>>(out, out_size);
    hungarian_wave<<<NBATCH / 2, 64, 0, stream>>>(pred, target, out);
}

// Round 5
// 1798.364 us; speedup vs baseline: 2.0509x; 2.0509x over previous
//
#include <hip/hip_runtime.h>

#define NPTS 256
#define NBATCH 64
#define BIGF 1e30f
#define KBIG 0x7149F200u   // __float_as_uint(1e30f) & 0xFFFFFF00

__device__ __forceinline__ float rlane(float v, int l) {
    return __uint_as_float((unsigned int)__builtin_amdgcn_readlane((int)__float_as_uint(v), l));
}
__device__ __forceinline__ int rlanei(int v, int l) {
    return __builtin_amdgcn_readlane(v, l);
}
__device__ __forceinline__ float rawsqrt(float x) {
    return __builtin_amdgcn_sqrtf(x);
}

// Uniform-slot select (slot wave-uniform); cold paths only.
#define SEL4(a, s) ((s) == 0 ? a[0] : (s) == 1 ? a[1] : (s) == 2 ? a[2] : a[3])

#define DPP_UMIN(v, ctrl) \
    (min)((v), (unsigned int)__builtin_amdgcn_update_dpp( \
        (int)(v), (int)(v), (ctrl), 0xf, 0xf, false))

__global__ void zero_out_kernel(float* out, int n) {
    int i = blockIdx.x * blockDim.x + threadIdx.x;
    if (i < n) out[i] = 0.0f;
}

// One expansion step of the delta-accumulated Dijkstra.
// R18: slots 0,1 relax from the LDS distance cache (pd01, prefetched last
// iteration); slots 2,3 computed — their math is the latency filler for the
// prefetch. Prefetch for the NEXT row (pc[j1], via one extra readlane in the
// existing switch) is issued after the free-test. Keys are bit-identical to
// R13 (cached d is the same rawsqrt of the same operands), so exactness and
// absmax 0.0 are preserved. Falsified levers: R14 duals (+406us), R15
// multi-source (+2000us), R16 free-argmin (h~0), R17 wave-ILP (0 overlap:
// single wave is issue-bound; only instruction count per extraction matters).
#define EXPAND_ONCE                                                              \
    {                                                                            \
        _Pragma("unroll")                                                        \
        for (int c = 2; c < 4; ++c) {                                            \
            float dx = bx - tx[c], dy = by - ty[c], dz = bz - tz[c];             \
            float d = rawsqrt(dx * dx + dy * dy + dz * dz);                      \
            float cand = d + w[c];              /* == d - ukey - vv[c] */        \
            unsigned int kc = (__float_as_uint(cand) & 0xFFFFFF00u) | colu[c];   \
            if (kc < kMv[c]) { kMv[c] = kc; way[c] = j0; }                       \
        }                                                                        \
        {                                                                        \
            float cand0 = pd01.x + w[0];                                         \
            unsigned int kc0 = (__float_as_uint(cand0) & 0xFFFFFF00u) | colu[0]; \
            if (kc0 < kMv[0]) { kMv[0] = kc0; way[0] = j0; }                     \
            float cand1 = pd01.y + w[1];                                         \
            unsigned int kc1 = (__float_as_uint(cand1) & 0xFFFFFF00u) | colu[1]; \
            if (kc1 < kMv[1]) { kMv[1] = kc1; way[1] = j0; }                     \
        }                                                                        \
        unsigned int vr = (min)((min)(kMv[0], kMv[1]), (min)(kMv[2], kMv[3]));   \
        vr = DPP_UMIN(vr, 0x111);   /* row_shr:1 */                              \
        vr = DPP_UMIN(vr, 0x112);   /* row_shr:2 */                              \
        vr = DPP_UMIN(vr, 0x114);   /* row_shr:4 */                              \
        const unsigned int q0 = (unsigned int)rlanei((int)vr, 7);                \
        const unsigned int q1 = (unsigned int)rlanei((int)vr, 15);               \
        const unsigned int q2 = (unsigned int)rlanei((int)vr, 23);               \
        const unsigned int q3 = (unsigned int)rlanei((int)vr, 31);               \
        const unsigned int q4 = (unsigned int)rlanei((int)vr, 39);               \
        const unsigned int q5 = (unsigned int)rlanei((int)vr, 47);               \
        const unsigned int q6 = (unsigned int)rlanei((int)vr, 55);               \
        const unsigned int q7 = (unsigned int)rlanei((int)vr, 63);               \
        const unsigned int kk = (min)((min)((min)(q0, q1), (min)(q2, q3)),       \
                                      (min)((min)(q4, q5), (min)(q6, q7)));      \
        const int   j1   = (int)(kk & 0xFFu);                                    \
        const float gmin = __uint_as_float(kk & 0xFFFFFF00u);                    \
        const int osl = j1 >> 6, oln = j1 & 63;                                  \
        float uj, nbx, nby, nbz; int prow;                                       \
        switch (osl) {                                                           \
            case 0:  uj = rlane(upc[0], oln); nbx = rlane(rxc[0], oln); nby = rlane(ryc[0], oln); nbz = rlane(rzc[0], oln); prow = rlanei(pc[0], oln); break; \
            case 1:  uj = rlane(upc[1], oln); nbx = rlane(rxc[1], oln); nby = rlane(ryc[1], oln); nbz = rlane(rzc[1], oln); prow = rlanei(pc[1], oln); break; \
            case 2:  uj = rlane(upc[2], oln); nbx = rlane(rxc[2], oln); nby = rlane(ryc[2], oln); nbz = rlane(rzc[2], oln); prow = rlanei(pc[2], oln); break; \
            default: uj = rlane(upc[3], oln); nbx = rlane(rxc[3], oln); nby = rlane(ryc[3], oln); nbz = rlane(rzc[3], oln); prow = rlanei(pc[3], oln); break; \
        }                                                                        \
        const unsigned long long fm =                                            \
            (osl == 0 ? freem[0] : osl == 1 ? freem[1] : osl == 2 ? freem[2] : freem[3]); \
        if ((fm >> oln) & 1ull) { jfin = j1; D = gmin; break; }                  \
        pd01 = dcache[prow * 64 + lane];    /* prefetch next row's d0,d1 */      \
        _Pragma("unroll")                                                        \
        for (int c = 0; c < 4; ++c)                                              \
            if (c == osl && lane == oln) {                                       \
                usedm |= (1 << c);                                               \
                Tv[c] = gmin;                                                    \
                vsave[c] = vv[c];                                                \
                vv[c] = -BIGF;                 /* -> w = +BIGF -> excluded */    \
                kMv[c] = KBIG | colu[c];       /* frozen */                      \
            }                                                                    \
        const float gu = gmin - uj;                                              \
        _Pragma("unroll")                                                        \
        for (int c = 0; c < 4; ++c) w[c] = gu - vv[c];                           \
        bx = nbx; by = nby; bz = nbz;                                            \
        j0 = j1;                                                                 \
    }

// One wave per batch; lane owns columns/rows {lane, 64+lane, 128+lane, 192+lane}.
// JV: column reduction -> greedy claim -> delta-accumulated Dijkstra searches.
// R18 = R13 + 128KB LDS f32 distance cache for column slots 0,1 (written for
// free during Phase 1a, which already computes all 256x256 distances), with
// software prefetch of the next tree-row's cached pair issued in the FETCH
// phase so slots-2,3 math hides the LDS latency.
__launch_bounds__(64, 1)
__global__ void hungarian_wave(const float* __restrict__ pred,
                               const float* __restrict__ target,
                               float* __restrict__ out) {
    const int b    = blockIdx.x;
    const int lane = threadIdx.x;

    __shared__ float2 dcache[NPTS * 64];   // [row][lane] -> d(row, lane), d(row, 64+lane); 128KB

    const float* pb = pred   + (size_t)b * NPTS * 3;
    const float* tb = target + (size_t)b * NPTS * 3;

    float prx[4], pry[4], prz[4];      // pred (row) points, row = c*64+lane
    float tx[4], ty[4], tz[4];         // target (col) points, col = c*64+lane
    float vv[4], upc[4], Tv[4], w[4], vsave[4];
    float rxc[4], ryc[4], rzc[4];      // matched-row coords, column-attached
    unsigned int kMv[4];               // packed slack keys: (bits(M)&~0xFF)|col
    int   pc[4]  = {-1, -1, -1, -1};   // matched row per column (-1 = free)
    int   way[4];
    unsigned int colu[4];              // this lane's column ids
    unsigned long long freem[4];       // free-COLUMN masks (wave-uniform)

#pragma unroll
    for (int c = 0; c < 4; ++c) {
        int idx = c * 64 + lane;
        prx[c] = pb[idx * 3 + 0]; pry[c] = pb[idx * 3 + 1]; prz[c] = pb[idx * 3 + 2];
        tx[c]  = tb[idx * 3 + 0]; ty[c]  = tb[idx * 3 + 1]; tz[c]  = tb[idx * 3 + 2];
        upc[c] = 0.f; Tv[c] = 0.f; vsave[c] = 0.f;
        rxc[c] = 0.f; ryc[c] = 0.f; rzc[c] = 0.f;
        colu[c] = (unsigned int)idx;
        freem[c] = ~0ull;
    }

    // ---- Phase 1a: column reduction + distance-cache fill for slots 0,1 ----
    float colmin[4] = {BIGF, BIGF, BIGF, BIGF};
    int   colrow[4] = {0, 0, 0, 0};
#pragma unroll
    for (int rs = 0; rs < 4; ++rs) {
        for (int rl = 0; rl < 64; ++rl) {
            float bx = rlane(prx[rs], rl), by = rlane(pry[rs], rl), bz = rlane(prz[rs], rl);
            int r = rs * 64 + rl;
            float dd[4];
#pragma unroll
            for (int c = 0; c < 4; ++c) {
                float dx = bx - tx[c], dy = by - ty[c], dz = bz - tz[c];
                dd[c] = rawsqrt(dx * dx + dy * dy + dz * dz);
                if (dd[c] < colmin[c]) { colmin[c] = dd[c]; colrow[c] = r; }
            }
            dcache[r * 64 + lane] = make_float2(dd[0], dd[1]);
        }
    }
#pragma unroll
    for (int c = 0; c < 4; ++c) vv[c] = colmin[c];
    __syncthreads();   // single wave: near-free; orders dcache writes vs reads

    // ---- Phase 1b: greedy claim — column (ascending) claims its argmin row if free ----
    unsigned long long frm[4];         // free-row masks (wave-uniform values)
    frm[0] = frm[1] = frm[2] = frm[3] = ~0ull;
#pragma unroll
    for (int cs = 0; cs < 4; ++cs) {
        for (int l = 0; l < 64; ++l) {
            int r = rlanei(colrow[cs], l);
            int rs = r >> 6, rl2 = r & 63;
            unsigned long long bit = 1ull << rl2;
            bool free_row = (SEL4(frm, rs) & bit) != 0ull;
            if (free_row) {
#pragma unroll
                for (int s = 0; s < 4; ++s)
                    if (s == rs) frm[s] &= ~bit;
                float bx, by, bz;
                switch (rs) {
                    case 0:  bx = rlane(prx[0], rl2); by = rlane(pry[0], rl2); bz = rlane(prz[0], rl2); break;
                    case 1:  bx = rlane(prx[1], rl2); by = rlane(pry[1], rl2); bz = rlane(prz[1], rl2); break;
                    case 2:  bx = rlane(prx[2], rl2); by = rlane(pry[2], rl2); bz = rlane(prz[2], rl2); break;
                    default: bx = rlane(prx[3], rl2); by = rlane(pry[3], rl2); bz = rlane(prz[3], rl2); break;
                }
                if (lane == l) {
                    pc[cs] = r; upc[cs] = 0.f;
                    rxc[cs] = bx; ryc[cs] = by; rzc[cs] = bz;
                }
#pragma unroll
                for (int s = 0; s < 4; ++s)
                    if (s == cs) freem[s] &= ~(1ull << l);   // column cs*64+l matched
            }
        }
    }

    // ---- Phase 2: Dijkstra shortest-path for remaining free rows ----
#pragma unroll
    for (int is = 0; is < 4; ++is) {
        unsigned long long m = frm[is];
        while (m) {
            const int il = (int)__builtin_ctzll(m);
            m &= (m - 1);
            const int i = is * 64 + il;

            float rootx, rooty, rootz;
            switch (is) {
                case 0:  rootx = rlane(prx[0], il); rooty = rlane(pry[0], il); rootz = rlane(prz[0], il); break;
                case 1:  rootx = rlane(prx[1], il); rooty = rlane(pry[1], il); rootz = rlane(prz[1], il); break;
                case 2:  rootx = rlane(prx[2], il); rooty = rlane(pry[2], il); rootz = rlane(prz[2], il); break;
                default: rootx = rlane(prx[3], il); rooty = rlane(pry[3], il); rootz = rlane(prz[3], il); break;
            }

#pragma unroll
            for (int c = 0; c < 4; ++c) {
                kMv[c] = KBIG | colu[c];
                w[c]   = -vv[c];
            }
            int usedm = 0;

            float bx = rootx, by = rooty, bz = rootz;
            float2 pd01 = dcache[i * 64 + lane];   // root row's cached d0,d1
            int j0 = -1;
            int jfin = 0;
            float D = 0.f;

            while (true) {
                EXPAND_ONCE
                EXPAND_ONCE
            }

            // Commit duals for tree columns: net amount = D_final - D_at_use
#pragma unroll
            for (int c = 0; c < 4; ++c)
                if ((usedm >> c) & 1) {
                    vv[c] = vsave[c] + Tv[c] - D;
                    upc[c] += D - Tv[c];
                }

            // Newly matched column leaves the free set
            {
                const int wsl = jfin >> 6;
                const unsigned long long bit = 1ull << (jfin & 63);
#pragma unroll
                for (int s = 0; s < 4; ++s)
                    if (s == wsl) freem[s] &= ~bit;
            }

            // Augment along alternating path (cold)
            int jc = jfin;
            while (true) {
                const int osl = jc >> 6, oln = jc & 63;
                int jw;
                switch (osl) {
                    case 0:  jw = rlanei(way[0], oln); break;
                    case 1:  jw = rlanei(way[1], oln); break;
                    case 2:  jw = rlanei(way[2], oln); break;
                    default: jw = rlanei(way[3], oln); break;
                }
                int np_; float nup, nrx, nry, nrz;
                if (jw < 0) {
                    np_ = i; nup = D; nrx = rootx; nry = rooty; nrz = rootz;
                } else {
                    const int wsl = jw >> 6, wln = jw & 63;
                    switch (wsl) {
                        case 0:  np_ = rlanei(pc[0], wln); nup = rlane(upc[0], wln); nrx = rlane(rxc[0], wln); nry = rlane(ryc[0], wln); nrz = rlane(rzc[0], wln); break;
                        case 1:  np_ = rlanei(pc[1], wln); nup = rlane(upc[1], wln); nrx = rlane(rxc[1], wln); nry = rlane(ryc[1], wln); nrz = rlane(rzc[1], wln); break;
                        case 2:  np_ = rlanei(pc[2], wln); nup = rlane(upc[2], wln); nrx = rlane(rxc[2], wln); nry = rlane(ryc[2], wln); nrz = rlane(rzc[2], wln); break;
                        default: np_ = rlanei(pc[3], wln); nup = rlane(upc[3], wln); nrx = rlane(rxc[3], wln); nry = rlane(ryc[3], wln); nrz = rlane(rzc[3], wln); break;
                    }
                }
#pragma unroll
                for (int c = 0; c < 4; ++c)
                    if (c == osl && lane == oln) {
                        pc[c] = np_; upc[c] = nup;
                        rxc[c] = nrx; ryc[c] = nry; rzc[c] = nrz;
                    }
                if (jw < 0) break;
                jc = jw;
            }
        }
    }

    // ---- Matched cost (coords column-attached; IEEE sqrt for final accuracy) ----
    float s = 0.f;
#pragma unroll
    for (int c = 0; c < 4; ++c) {
        float dx = rxc[c] - tx[c], dy = ryc[c] - ty[c], dz = rzc[c] - tz[c];
        s += sqrtf(dx * dx + dy * dy + dz * dz);
    }
#pragma unroll
    for (int off = 1; off < 64; off <<= 1) s += __shfl_xor(s, off, 64);
    if (lane == 0) atomicAdd(out, s / (float)NBATCH);
}

extern "C" void kernel_launch(void* const* d_in, const int* in_sizes, int n_in,
                              void* d_out, int out_size, void* d_ws, size_t ws_size,
                              hipStream_t stream) {
    const float* pred   = (const float*)d_in[0];
    const float* target = (const float*)d_in[1];
    float* out = (float*)d_out;

    zero_out_kernel<<<1, 64, 0, stream>>>(out, out_size);
    hungarian_wave<<<NBATCH, 64, 0, stream>>>(pred, target, out);
}

// Round 6
// 1782.866 us; speedup vs baseline: 2.0688x; 1.0087x over previous
//
#include <hip/hip_runtime.h>

#define NPTS 256
#define NBATCH 64
#define BIGF 1e30f
#define KBIG 0x7149F200u   // __float_as_uint(1e30f) & 0xFFFFFF00

__device__ __forceinline__ float rlane(float v, int l) {
    return __uint_as_float((unsigned int)__builtin_amdgcn_readlane((int)__float_as_uint(v), l));
}
__device__ __forceinline__ int rlanei(int v, int l) {
    return __builtin_amdgcn_readlane(v, l);
}
__device__ __forceinline__ float rawsqrt(float x) {
    return __builtin_amdgcn_sqrtf(x);
}

// Uniform-slot select (slot wave-uniform); cold paths only.
#define SEL4(a, s) ((s) == 0 ? a[0] : (s) == 1 ? a[1] : (s) == 2 ? a[2] : a[3])

#define DPP_UMIN(v, ctrl) \
    (min)((v), (unsigned int)__builtin_amdgcn_update_dpp( \
        (int)(v), (int)(v), (ctrl), 0xf, 0xf, false))

__global__ void zero_out_kernel(float* out, int n) {
    int i = blockIdx.x * blockDim.x + threadIdx.x;
    if (i < n) out[i] = 0.0f;
}

// One expansion step of the delta-accumulated Dijkstra.
// R18: slots 0,1 relax from the LDS distance cache (pd01, prefetched last
// iteration); slots 2,3 computed — their math is the latency filler for the
// prefetch. R19: reduce shortened to 4 DPP row_shr stages (1,2,4,8 -> full
// 16-lane-row minima at lanes 15,31,47,63) + 4 readlanes + 3 SALU mins,
// replacing 3 DPP + 8 readlanes + 7 mins. Min is associative: keys and
// assignment bit-identical, absmax 0.0 preserved.
// Calibrated model (R17/R18): single wave is issue-bound; dur moves 1:1 with
// net issue-cycles per extraction (~161 cy now). Falsified levers: R14 duals,
// R15 multi-source, R16 free-argmin (h~0), R17 wave-ILP (no overlap).
#define EXPAND_ONCE                                                              \
    {                                                                            \
        _Pragma("unroll")                                                        \
        for (int c = 2; c < 4; ++c) {                                            \
            float dx = bx - tx[c], dy = by - ty[c], dz = bz - tz[c];             \
            float d = rawsqrt(dx * dx + dy * dy + dz * dz);                      \
            float cand = d + w[c];              /* == d - ukey - vv[c] */        \
            unsigned int kc = (__float_as_uint(cand) & 0xFFFFFF00u) | colu[c];   \
            if (kc < kMv[c]) { kMv[c] = kc; way[c] = j0; }                       \
        }                                                                        \
        {                                                                        \
            float cand0 = pd01.x + w[0];                                         \
            unsigned int kc0 = (__float_as_uint(cand0) & 0xFFFFFF00u) | colu[0]; \
            if (kc0 < kMv[0]) { kMv[0] = kc0; way[0] = j0; }                     \
            float cand1 = pd01.y + w[1];                                         \
            unsigned int kc1 = (__float_as_uint(cand1) & 0xFFFFFF00u) | colu[1]; \
            if (kc1 < kMv[1]) { kMv[1] = kc1; way[1] = j0; }                     \
        }                                                                        \
        unsigned int vr = (min)((min)(kMv[0], kMv[1]), (min)(kMv[2], kMv[3]));   \
        vr = DPP_UMIN(vr, 0x111);   /* row_shr:1 */                              \
        vr = DPP_UMIN(vr, 0x112);   /* row_shr:2 */                              \
        vr = DPP_UMIN(vr, 0x114);   /* row_shr:4 */                              \
        vr = DPP_UMIN(vr, 0x118);   /* row_shr:8 -> lane15/31/47/63 = row min */ \
        const unsigned int q0 = (unsigned int)rlanei((int)vr, 15);               \
        const unsigned int q1 = (unsigned int)rlanei((int)vr, 31);               \
        const unsigned int q2 = (unsigned int)rlanei((int)vr, 47);               \
        const unsigned int q3 = (unsigned int)rlanei((int)vr, 63);               \
        const unsigned int kk = (min)((min)(q0, q1), (min)(q2, q3));             \
        const int   j1   = (int)(kk & 0xFFu);                                    \
        const float gmin = __uint_as_float(kk & 0xFFFFFF00u);                    \
        const int osl = j1 >> 6, oln = j1 & 63;                                  \
        float uj, nbx, nby, nbz; int prow;                                       \
        switch (osl) {                                                           \
            case 0:  uj = rlane(upc[0], oln); nbx = rlane(rxc[0], oln); nby = rlane(ryc[0], oln); nbz = rlane(rzc[0], oln); prow = rlanei(pc[0], oln); break; \
            case 1:  uj = rlane(upc[1], oln); nbx = rlane(rxc[1], oln); nby = rlane(ryc[1], oln); nbz = rlane(rzc[1], oln); prow = rlanei(pc[1], oln); break; \
            case 2:  uj = rlane(upc[2], oln); nbx = rlane(rxc[2], oln); nby = rlane(ryc[2], oln); nbz = rlane(rzc[2], oln); prow = rlanei(pc[2], oln); break; \
            default: uj = rlane(upc[3], oln); nbx = rlane(rxc[3], oln); nby = rlane(ryc[3], oln); nbz = rlane(rzc[3], oln); prow = rlanei(pc[3], oln); break; \
        }                                                                        \
        const unsigned long long fm =                                            \
            (osl == 0 ? freem[0] : osl == 1 ? freem[1] : osl == 2 ? freem[2] : freem[3]); \
        if ((fm >> oln) & 1ull) { jfin = j1; D = gmin; break; }                  \
        pd01 = dcache[prow * 64 + lane];    /* prefetch next row's d0,d1 */      \
        _Pragma("unroll")                                                        \
        for (int c = 0; c < 4; ++c)                                              \
            if (c == osl && lane == oln) {                                       \
                usedm |= (1 << c);                                               \
                Tv[c] = gmin;                                                    \
                vsave[c] = vv[c];                                                \
                vv[c] = -BIGF;                 /* -> w = +BIGF -> excluded */    \
                kMv[c] = KBIG | colu[c];       /* frozen */                      \
            }                                                                    \
        const float gu = gmin - uj;                                              \
        _Pragma("unroll")                                                        \
        for (int c = 0; c < 4; ++c) w[c] = gu - vv[c];                           \
        bx = nbx; by = nby; bz = nbz;                                            \
        j0 = j1;                                                                 \
    }

// One wave per batch; lane owns columns/rows {lane, 64+lane, 128+lane, 192+lane}.
// JV: column reduction -> greedy claim -> delta-accumulated Dijkstra searches.
// R19 = R18 (128KB LDS f32 distance cache for column slots 0,1, filled free
// during Phase 1a, prefetched one extraction ahead) + 4-DPP/4-readlane reduce.
__launch_bounds__(64, 1)
__global__ void hungarian_wave(const float* __restrict__ pred,
                               const float* __restrict__ target,
                               float* __restrict__ out) {
    const int b    = blockIdx.x;
    const int lane = threadIdx.x;

    __shared__ float2 dcache[NPTS * 64];   // [row][lane] -> d(row, lane), d(row, 64+lane); 128KB

    const float* pb = pred   + (size_t)b * NPTS * 3;
    const float* tb = target + (size_t)b * NPTS * 3;

    float prx[4], pry[4], prz[4];      // pred (row) points, row = c*64+lane
    float tx[4], ty[4], tz[4];         // target (col) points, col = c*64+lane
    float vv[4], upc[4], Tv[4], w[4], vsave[4];
    float rxc[4], ryc[4], rzc[4];      // matched-row coords, column-attached
    unsigned int kMv[4];               // packed slack keys: (bits(M)&~0xFF)|col
    int   pc[4]  = {-1, -1, -1, -1};   // matched row per column (-1 = free)
    int   way[4];
    unsigned int colu[4];              // this lane's column ids
    unsigned long long freem[4];       // free-COLUMN masks (wave-uniform)

#pragma unroll
    for (int c = 0; c < 4; ++c) {
        int idx = c * 64 + lane;
        prx[c] = pb[idx * 3 + 0]; pry[c] = pb[idx * 3 + 1]; prz[c] = pb[idx * 3 + 2];
        tx[c]  = tb[idx * 3 + 0]; ty[c]  = tb[idx * 3 + 1]; tz[c]  = tb[idx * 3 + 2];
        upc[c] = 0.f; Tv[c] = 0.f; vsave[c] = 0.f;
        rxc[c] = 0.f; ryc[c] = 0.f; rzc[c] = 0.f;
        colu[c] = (unsigned int)idx;
        freem[c] = ~0ull;
    }

    // ---- Phase 1a: column reduction + distance-cache fill for slots 0,1 ----
    float colmin[4] = {BIGF, BIGF, BIGF, BIGF};
    int   colrow[4] = {0, 0, 0, 0};
#pragma unroll
    for (int rs = 0; rs < 4; ++rs) {
        for (int rl = 0; rl < 64; ++rl) {
            float bx = rlane(prx[rs], rl), by = rlane(pry[rs], rl), bz = rlane(prz[rs], rl);
            int r = rs * 64 + rl;
            float dd[4];
#pragma unroll
            for (int c = 0; c < 4; ++c) {
                float dx = bx - tx[c], dy = by - ty[c], dz = bz - tz[c];
                dd[c] = rawsqrt(dx * dx + dy * dy + dz * dz);
                if (dd[c] < colmin[c]) { colmin[c] = dd[c]; colrow[c] = r; }
            }
            dcache[r * 64 + lane] = make_float2(dd[0], dd[1]);
        }
    }
#pragma unroll
    for (int c = 0; c < 4; ++c) vv[c] = colmin[c];
    __syncthreads();   // single wave: near-free; orders dcache writes vs reads

    // ---- Phase 1b: greedy claim — column (ascending) claims its argmin row if free ----
    unsigned long long frm[4];         // free-row masks (wave-uniform values)
    frm[0] = frm[1] = frm[2] = frm[3] = ~0ull;
#pragma unroll
    for (int cs = 0; cs < 4; ++cs) {
        for (int l = 0; l < 64; ++l) {
            int r = rlanei(colrow[cs], l);
            int rs = r >> 6, rl2 = r & 63;
            unsigned long long bit = 1ull << rl2;
            bool free_row = (SEL4(frm, rs) & bit) != 0ull;
            if (free_row) {
#pragma unroll
                for (int s = 0; s < 4; ++s)
                    if (s == rs) frm[s] &= ~bit;
                float bx, by, bz;
                switch (rs) {
                    case 0:  bx = rlane(prx[0], rl2); by = rlane(pry[0], rl2); bz = rlane(prz[0], rl2); break;
                    case 1:  bx = rlane(prx[1], rl2); by = rlane(pry[1], rl2); bz = rlane(prz[1], rl2); break;
                    case 2:  bx = rlane(prx[2], rl2); by = rlane(pry[2], rl2); bz = rlane(prz[2], rl2); break;
                    default: bx = rlane(prx[3], rl2); by = rlane(pry[3], rl2); bz = rlane(prz[3], rl2); break;
                }
                if (lane == l) {
                    pc[cs] = r; upc[cs] = 0.f;
                    rxc[cs] = bx; ryc[cs] = by; rzc[cs] = bz;
                }
#pragma unroll
                for (int s = 0; s < 4; ++s)
                    if (s == cs) freem[s] &= ~(1ull << l);   // column cs*64+l matched
            }
        }
    }

    // ---- Phase 2: Dijkstra shortest-path for remaining free rows ----
#pragma unroll
    for (int is = 0; is < 4; ++is) {
        unsigned long long m = frm[is];
        while (m) {
            const int il = (int)__builtin_ctzll(m);
            m &= (m - 1);
            const int i = is * 64 + il;

            float rootx, rooty, rootz;
            switch (is) {
                case 0:  rootx = rlane(prx[0], il); rooty = rlane(pry[0], il); rootz = rlane(prz[0], il); break;
                case 1:  rootx = rlane(prx[1], il); rooty = rlane(pry[1], il); rootz = rlane(prz[1], il); break;
                case 2:  rootx = rlane(prx[2], il); rooty = rlane(pry[2], il); rootz = rlane(prz[2], il); break;
                default: rootx = rlane(prx[3], il); rooty = rlane(pry[3], il); rootz = rlane(prz[3], il); break;
            }

#pragma unroll
            for (int c = 0; c < 4; ++c) {
                kMv[c] = KBIG | colu[c];
                w[c]   = -vv[c];
            }
            int usedm = 0;

            float bx = rootx, by = rooty, bz = rootz;
            float2 pd01 = dcache[i * 64 + lane];   // root row's cached d0,d1
            int j0 = -1;
            int jfin = 0;
            float D = 0.f;

            while (true) {
                EXPAND_ONCE
                EXPAND_ONCE
            }

            // Commit duals for tree columns: net amount = D_final - D_at_use
#pragma unroll
            for (int c = 0; c < 4; ++c)
                if ((usedm >> c) & 1) {
                    vv[c] = vsave[c] + Tv[c] - D;
                    upc[c] += D - Tv[c];
                }

            // Newly matched column leaves the free set
            {
                const int wsl = jfin >> 6;
                const unsigned long long bit = 1ull << (jfin & 63);
#pragma unroll
                for (int s = 0; s < 4; ++s)
                    if (s == wsl) freem[s] &= ~bit;
            }

            // Augment along alternating path (cold)
            int jc = jfin;
            while (true) {
                const int osl = jc >> 6, oln = jc & 63;
                int jw;
                switch (osl) {
                    case 0:  jw = rlanei(way[0], oln); break;
                    case 1:  jw = rlanei(way[1], oln); break;
                    case 2:  jw = rlanei(way[2], oln); break;
                    default: jw = rlanei(way[3], oln); break;
                }
                int np_; float nup, nrx, nry, nrz;
                if (jw < 0) {
                    np_ = i; nup = D; nrx = rootx; nry = rooty; nrz = rootz;
                } else {
                    const int wsl = jw >> 6, wln = jw & 63;
                    switch (wsl) {
                        case 0:  np_ = rlanei(pc[0], wln); nup = rlane(upc[0], wln); nrx = rlane(rxc[0], wln); nry = rlane(ryc[0], wln); nrz = rlane(rzc[0], wln); break;
                        case 1:  np_ = rlanei(pc[1], wln); nup = rlane(upc[1], wln); nrx = rlane(rxc[1], wln); nry = rlane(ryc[1], wln); nrz = rlane(rzc[1], wln); break;
                        case 2:  np_ = rlanei(pc[2], wln); nup = rlane(upc[2], wln); nrx = rlane(rxc[2], wln); nry = rlane(ryc[2], wln); nrz = rlane(rzc[2], wln); break;
                        default: np_ = rlanei(pc[3], wln); nup = rlane(upc[3], wln); nrx = rlane(rxc[3], wln); nry = rlane(ryc[3], wln); nrz = rlane(rzc[3], wln); break;
                    }
                }
#pragma unroll
                for (int c = 0; c < 4; ++c)
                    if (c == osl && lane == oln) {
                        pc[c] = np_; upc[c] = nup;
                        rxc[c] = nrx; ryc[c] = nry; rzc[c] = nrz;
                    }
                if (jw < 0) break;
                jc = jw;
            }
        }
    }

    // ---- Matched cost (coords column-attached; IEEE sqrt for final accuracy) ----
    float s = 0.f;
#pragma unroll
    for (int c = 0; c < 4; ++c) {
        float dx = rxc[c] - tx[c], dy = ryc[c] - ty[c], dz = rzc[c] - tz[c];
        s += sqrtf(dx * dx + dy * dy + dz * dz);
    }
#pragma unroll
    for (int off = 1; off < 64; off <<= 1) s += __shfl_xor(s, off, 64);
    if (lane == 0) atomicAdd(out, s / (float)NBATCH);
}

extern "C" void kernel_launch(void* const* d_in, const int* in_sizes, int n_in,
                              void* d_out, int out_size, void* d_ws, size_t ws_size,
                              hipStream_t stream) {
    const float* pred   = (const float*)d_in[0];
    const float* target = (const float*)d_in[1];
    float* out = (float*)d_out;

    zero_out_kernel<<<1, 64, 0, stream>>>(out, out_size);
    hungarian_wave<<<NBATCH, 64, 0, stream>>>(pred, target, out);
}

// Round 7
// 1682.372 us; speedup vs baseline: 2.1923x; 1.0597x over previous
//
#include <hip/hip_runtime.h>

#define NPTS 256
#define NBATCH 64
#define BIGF 1e30f
#define KBIG 0x7149F200u   // __float_as_uint(1e30f) & 0xFFFFFF00

__device__ __forceinline__ float rlane(float v, int l) {
    return __uint_as_float((unsigned int)__builtin_amdgcn_readlane((int)__float_as_uint(v), l));
}
__device__ __forceinline__ int rlanei(int v, int l) {
    return __builtin_amdgcn_readlane(v, l);
}
__device__ __forceinline__ float rawsqrt(float x) {
    return __builtin_amdgcn_sqrtf(x);
}

// Uniform-slot select (slot wave-uniform); cold paths only.
#define SEL4(a, s) ((s) == 0 ? a[0] : (s) == 1 ? a[1] : (s) == 2 ? a[2] : a[3])

#define DPP_UMIN(v, ctrl) \
    (min)((v), (unsigned int)__builtin_amdgcn_update_dpp( \
        (int)(v), (int)(v), (ctrl), 0xf, 0xf, false))

__global__ void zero_out_kernel(float* out, int n) {
    int i = blockIdx.x * blockDim.x + threadIdx.x;
    if (i < n) out[i] = 0.0f;
}

// One expansion step of the delta-accumulated Dijkstra.
// R18: slots 0,1 relax from the LDS distance cache (pd01, prefetched last
// iteration); slots 2,3 computed — filler for the prefetch latency.
// R19: 4-DPP (row_shr 1,2,4,8) + 4-readlane reduce (min associative: bit-identical).
// R20: free-test FIRST, then ONE merged switch(osl) doing fetch readlanes +
// pd01 prefetch + freeze writes (lane==oln predicated). Deletes the second
// scalar branch cascade (the old per-c freeze loop) — ~10-16 cy/extraction of
// SALU+branch-bubble overhead. Update conditions identical (c==osl via switch
// arm), same write order (vv before w recompute): bit-exact vs R19.
// Calibrated model (R17-R19): single wave, in-order; dur moves 1:1 with net
// issue+stall cycles per extraction (~173 cy now). Falsified: R14 duals, R15
// multi-source, R16 free-argmin, R17 wave-ILP.
#define EXPAND_ONCE                                                              \
    {                                                                            \
        _Pragma("unroll")                                                        \
        for (int c = 2; c < 4; ++c) {                                            \
            float dx = bx - tx[c], dy = by - ty[c], dz = bz - tz[c];             \
            float d = rawsqrt(dx * dx + dy * dy + dz * dz);                      \
            float cand = d + w[c];              /* == d - ukey - vv[c] */        \
            unsigned int kc = (__float_as_uint(cand) & 0xFFFFFF00u) | colu[c];   \
            if (kc < kMv[c]) { kMv[c] = kc; way[c] = j0; }                       \
        }                                                                        \
        {                                                                        \
            float cand0 = pd01.x + w[0];                                         \
            unsigned int kc0 = (__float_as_uint(cand0) & 0xFFFFFF00u) | colu[0]; \
            if (kc0 < kMv[0]) { kMv[0] = kc0; way[0] = j0; }                     \
            float cand1 = pd01.y + w[1];                                         \
            unsigned int kc1 = (__float_as_uint(cand1) & 0xFFFFFF00u) | colu[1]; \
            if (kc1 < kMv[1]) { kMv[1] = kc1; way[1] = j0; }                     \
        }                                                                        \
        unsigned int vr = (min)((min)(kMv[0], kMv[1]), (min)(kMv[2], kMv[3]));   \
        vr = DPP_UMIN(vr, 0x111);   /* row_shr:1 */                              \
        vr = DPP_UMIN(vr, 0x112);   /* row_shr:2 */                              \
        vr = DPP_UMIN(vr, 0x114);   /* row_shr:4 */                              \
        vr = DPP_UMIN(vr, 0x118);   /* row_shr:8 -> lane15/31/47/63 = row min */ \
        const unsigned int q0 = (unsigned int)rlanei((int)vr, 15);               \
        const unsigned int q1 = (unsigned int)rlanei((int)vr, 31);               \
        const unsigned int q2 = (unsigned int)rlanei((int)vr, 47);               \
        const unsigned int q3 = (unsigned int)rlanei((int)vr, 63);               \
        const unsigned int kk = (min)((min)(q0, q1), (min)(q2, q3));             \
        const int   j1   = (int)(kk & 0xFFu);                                    \
        const float gmin = __uint_as_float(kk & 0xFFFFFF00u);                    \
        const int osl = j1 >> 6, oln = j1 & 63;                                  \
        const unsigned long long fm = SEL4(freem, osl);                          \
        if ((fm >> oln) & 1ull) { jfin = j1; D = gmin; break; }                  \
        float uj, nbx, nby, nbz; int prow;                                       \
        switch (osl) {                                                           \
            case 0:                                                              \
                uj = rlane(upc[0], oln); nbx = rlane(rxc[0], oln);               \
                nby = rlane(ryc[0], oln); nbz = rlane(rzc[0], oln);              \
                prow = rlanei(pc[0], oln);                                       \
                pd01 = dcache[prow * 64 + lane];                                 \
                if (lane == oln) {                                               \
                    usedm |= 1; Tv[0] = gmin; vsave[0] = vv[0];                  \
                    vv[0] = -BIGF; kMv[0] = KBIG | colu[0];                      \
                }                                                                \
                break;                                                           \
            case 1:                                                              \
                uj = rlane(upc[1], oln); nbx = rlane(rxc[1], oln);               \
                nby = rlane(ryc[1], oln); nbz = rlane(rzc[1], oln);              \
                prow = rlanei(pc[1], oln);                                       \
                pd01 = dcache[prow * 64 + lane];                                 \
                if (lane == oln) {                                               \
                    usedm |= 2; Tv[1] = gmin; vsave[1] = vv[1];                  \
                    vv[1] = -BIGF; kMv[1] = KBIG | colu[1];                      \
                }                                                                \
                break;                                                           \
            case 2:                                                              \
                uj = rlane(upc[2], oln); nbx = rlane(rxc[2], oln);               \
                nby = rlane(ryc[2], oln); nbz = rlane(rzc[2], oln);              \
                prow = rlanei(pc[2], oln);                                       \
                pd01 = dcache[prow * 64 + lane];                                 \
                if (lane == oln) {                                               \
                    usedm |= 4; Tv[2] = gmin; vsave[2] = vv[2];                  \
                    vv[2] = -BIGF; kMv[2] = KBIG | colu[2];                      \
                }                                                                \
                break;                                                           \
            default:                                                             \
                uj = rlane(upc[3], oln); nbx = rlane(rxc[3], oln);               \
                nby = rlane(ryc[3], oln); nbz = rlane(rzc[3], oln);              \
                prow = rlanei(pc[3], oln);                                       \
                pd01 = dcache[prow * 64 + lane];                                 \
                if (lane == oln) {                                               \
                    usedm |= 8; Tv[3] = gmin; vsave[3] = vv[3];                  \
                    vv[3] = -BIGF; kMv[3] = KBIG | colu[3];                      \
                }                                                                \
                break;                                                           \
        }                                                                        \
        const float gu = gmin - uj;                                              \
        _Pragma("unroll")                                                        \
        for (int c = 0; c < 4; ++c) w[c] = gu - vv[c];                           \
        bx = nbx; by = nby; bz = nbz;                                            \
        j0 = j1;                                                                 \
    }

// One wave per batch; lane owns columns/rows {lane, 64+lane, 128+lane, 192+lane}.
// JV: column reduction -> greedy claim -> delta-accumulated Dijkstra searches.
// R20 = R19 (128KB LDS distance cache slots 0,1 + 4-DPP reduce) + merged
// fetch/freeze switch with early free-test.
__launch_bounds__(64, 1)
__global__ void hungarian_wave(const float* __restrict__ pred,
                               const float* __restrict__ target,
                               float* __restrict__ out) {
    const int b    = blockIdx.x;
    const int lane = threadIdx.x;

    __shared__ float2 dcache[NPTS * 64];   // [row][lane] -> d(row, lane), d(row, 64+lane); 128KB

    const float* pb = pred   + (size_t)b * NPTS * 3;
    const float* tb = target + (size_t)b * NPTS * 3;

    float prx[4], pry[4], prz[4];      // pred (row) points, row = c*64+lane
    float tx[4], ty[4], tz[4];         // target (col) points, col = c*64+lane
    float vv[4], upc[4], Tv[4], w[4], vsave[4];
    float rxc[4], ryc[4], rzc[4];      // matched-row coords, column-attached
    unsigned int kMv[4];               // packed slack keys: (bits(M)&~0xFF)|col
    int   pc[4]  = {-1, -1, -1, -1};   // matched row per column (-1 = free)
    int   way[4];
    unsigned int colu[4];              // this lane's column ids
    unsigned long long freem[4];       // free-COLUMN masks (wave-uniform)

#pragma unroll
    for (int c = 0; c < 4; ++c) {
        int idx = c * 64 + lane;
        prx[c] = pb[idx * 3 + 0]; pry[c] = pb[idx * 3 + 1]; prz[c] = pb[idx * 3 + 2];
        tx[c]  = tb[idx * 3 + 0]; ty[c]  = tb[idx * 3 + 1]; tz[c]  = tb[idx * 3 + 2];
        upc[c] = 0.f; Tv[c] = 0.f; vsave[c] = 0.f;
        rxc[c] = 0.f; ryc[c] = 0.f; rzc[c] = 0.f;
        colu[c] = (unsigned int)idx;
        freem[c] = ~0ull;
    }

    // ---- Phase 1a: column reduction + distance-cache fill for slots 0,1 ----
    float colmin[4] = {BIGF, BIGF, BIGF, BIGF};
    int   colrow[4] = {0, 0, 0, 0};
#pragma unroll
    for (int rs = 0; rs < 4; ++rs) {
        for (int rl = 0; rl < 64; ++rl) {
            float bx = rlane(prx[rs], rl), by = rlane(pry[rs], rl), bz = rlane(prz[rs], rl);
            int r = rs * 64 + rl;
            float dd[4];
#pragma unroll
            for (int c = 0; c < 4; ++c) {
                float dx = bx - tx[c], dy = by - ty[c], dz = bz - tz[c];
                dd[c] = rawsqrt(dx * dx + dy * dy + dz * dz);
                if (dd[c] < colmin[c]) { colmin[c] = dd[c]; colrow[c] = r; }
            }
            dcache[r * 64 + lane] = make_float2(dd[0], dd[1]);
        }
    }
#pragma unroll
    for (int c = 0; c < 4; ++c) vv[c] = colmin[c];
    __syncthreads();   // single wave: near-free; orders dcache writes vs reads

    // ---- Phase 1b: greedy claim — column (ascending) claims its argmin row if free ----
    unsigned long long frm[4];         // free-row masks (wave-uniform values)
    frm[0] = frm[1] = frm[2] = frm[3] = ~0ull;
#pragma unroll
    for (int cs = 0; cs < 4; ++cs) {
        for (int l = 0; l < 64; ++l) {
            int r = rlanei(colrow[cs], l);
            int rs = r >> 6, rl2 = r & 63;
            unsigned long long bit = 1ull << rl2;
            bool free_row = (SEL4(frm, rs) & bit) != 0ull;
            if (free_row) {
#pragma unroll
                for (int s = 0; s < 4; ++s)
                    if (s == rs) frm[s] &= ~bit;
                float bx, by, bz;
                switch (rs) {
                    case 0:  bx = rlane(prx[0], rl2); by = rlane(pry[0], rl2); bz = rlane(prz[0], rl2); break;
                    case 1:  bx = rlane(prx[1], rl2); by = rlane(pry[1], rl2); bz = rlane(prz[1], rl2); break;
                    case 2:  bx = rlane(prx[2], rl2); by = rlane(pry[2], rl2); bz = rlane(prz[2], rl2); break;
                    default: bx = rlane(prx[3], rl2); by = rlane(pry[3], rl2); bz = rlane(prz[3], rl2); break;
                }
                if (lane == l) {
                    pc[cs] = r; upc[cs] = 0.f;
                    rxc[cs] = bx; ryc[cs] = by; rzc[cs] = bz;
                }
#pragma unroll
                for (int s = 0; s < 4; ++s)
                    if (s == cs) freem[s] &= ~(1ull << l);   // column cs*64+l matched
            }
        }
    }

    // ---- Phase 2: Dijkstra shortest-path for remaining free rows ----
#pragma unroll
    for (int is = 0; is < 4; ++is) {
        unsigned long long m = frm[is];
        while (m) {
            const int il = (int)__builtin_ctzll(m);
            m &= (m - 1);
            const int i = is * 64 + il;

            float rootx, rooty, rootz;
            switch (is) {
                case 0:  rootx = rlane(prx[0], il); rooty = rlane(pry[0], il); rootz = rlane(prz[0], il); break;
                case 1:  rootx = rlane(prx[1], il); rooty = rlane(pry[1], il); rootz = rlane(prz[1], il); break;
                case 2:  rootx = rlane(prx[2], il); rooty = rlane(pry[2], il); rootz = rlane(prz[2], il); break;
                default: rootx = rlane(prx[3], il); rooty = rlane(pry[3], il); rootz = rlane(prz[3], il); break;
            }

#pragma unroll
            for (int c = 0; c < 4; ++c) {
                kMv[c] = KBIG | colu[c];
                w[c]   = -vv[c];
            }
            int usedm = 0;

            float bx = rootx, by = rooty, bz = rootz;
            float2 pd01 = dcache[i * 64 + lane];   // root row's cached d0,d1
            int j0 = -1;
            int jfin = 0;
            float D = 0.f;

            while (true) {
                EXPAND_ONCE
                EXPAND_ONCE
            }

            // Commit duals for tree columns: net amount = D_final - D_at_use
#pragma unroll
            for (int c = 0; c < 4; ++c)
                if ((usedm >> c) & 1) {
                    vv[c] = vsave[c] + Tv[c] - D;
                    upc[c] += D - Tv[c];
                }

            // Newly matched column leaves the free set
            {
                const int wsl = jfin >> 6;
                const unsigned long long bit = 1ull << (jfin & 63);
#pragma unroll
                for (int s = 0; s < 4; ++s)
                    if (s == wsl) freem[s] &= ~bit;
            }

            // Augment along alternating path (cold)
            int jc = jfin;
            while (true) {
                const int osl = jc >> 6, oln = jc & 63;
                int jw;
                switch (osl) {
                    case 0:  jw = rlanei(way[0], oln); break;
                    case 1:  jw = rlanei(way[1], oln); break;
                    case 2:  jw = rlanei(way[2], oln); break;
                    default: jw = rlanei(way[3], oln); break;
                }
                int np_; float nup, nrx, nry, nrz;
                if (jw < 0) {
                    np_ = i; nup = D; nrx = rootx; nry = rooty; nrz = rootz;
                } else {
                    const int wsl = jw >> 6, wln = jw & 63;
                    switch (wsl) {
                        case 0:  np_ = rlanei(pc[0], wln); nup = rlane(upc[0], wln); nrx = rlane(rxc[0], wln); nry = rlane(ryc[0], wln); nrz = rlane(rzc[0], wln); break;
                        case 1:  np_ = rlanei(pc[1], wln); nup = rlane(upc[1], wln); nrx = rlane(rxc[1], wln); nry = rlane(ryc[1], wln); nrz = rlane(rzc[1], wln); break;
                        case 2:  np_ = rlanei(pc[2], wln); nup = rlane(upc[2], wln); nrx = rlane(rxc[2], wln); nry = rlane(ryc[2], wln); nrz = rlane(rzc[2], wln); break;
                        default: np_ = rlanei(pc[3], wln); nup = rlane(upc[3], wln); nrx = rlane(rxc[3], wln); nry = rlane(ryc[3], wln); nrz = rlane(rzc[3], wln); break;
                    }
                }
#pragma unroll
                for (int c = 0; c < 4; ++c)
                    if (c == osl && lane == oln) {
                        pc[c] = np_; upc[c] = nup;
                        rxc[c] = nrx; ryc[c] = nry; rzc[c] = nrz;
                    }
                if (jw < 0) break;
                jc = jw;
            }
        }
    }

    // ---- Matched cost (coords column-attached; IEEE sqrt for final accuracy) ----
    float s = 0.f;
#pragma unroll
    for (int c = 0; c < 4; ++c) {
        float dx = rxc[c] - tx[c], dy = ryc[c] - ty[c], dz = rzc[c] - tz[c];
        s += sqrtf(dx * dx + dy * dy + dz * dz);
    }
#pragma unroll
    for (int off = 1; off < 64; off <<= 1) s += __shfl_xor(s, off, 64);
    if (lane == 0) atomicAdd(out, s / (float)NBATCH);
}

extern "C" void kernel_launch(void* const* d_in, const int* in_sizes, int n_in,
                              void* d_out, int out_size, void* d_ws, size_t ws_size,
                              hipStream_t stream) {
    const float* pred   = (const float*)d_in[0];
    const float* target = (const float*)d_in[1];
    float* out = (float*)d_out;

    zero_out_kernel<<<1, 64, 0, stream>>>(out, out_size);
    hungarian_wave<<<NBATCH, 64, 0, stream>>>(pred, target, out);
}